// Round 16
// baseline (266.750 us; speedup 1.0000x reference)
//
#include <hip/hip_runtime.h>
#include <hip/hip_bf16.h>

#define N_BOXES 8192
#define NW 128            // number of 64-box chunks / 64-bit words per row
#define NREG 64           // regions (one chunk PAIR per region)
#define FEAT 10
#define NSLOT 8           // row slots per worker lane per chunk

typedef unsigned long long u64;
typedef unsigned int u32;

__device__ __forceinline__ void barrier_nodrain() {
    asm volatile("s_waitcnt lgkmcnt(0)" ::: "memory");
    __builtin_amdgcn_sched_barrier(0);
    __builtin_amdgcn_s_barrier();
    __builtin_amdgcn_sched_barrier(0);
    asm volatile("" ::: "memory");
}

// ---------------- Phase A: rank + scatter sorted boxes ----------------
__global__ void rank_scatter_kernel(const float* __restrict__ bboxes,
                                    const float* __restrict__ scores,
                                    float* __restrict__ x1s, float* __restrict__ y1s,
                                    float* __restrict__ x2s, float* __restrict__ y2s,
                                    u32* __restrict__ rank_of) {
    __shared__ float sc[N_BOXES];
    int tid = threadIdx.x;
    for (int t = 0; t < N_BOXES / 256; ++t)
        sc[tid + 256 * t] = scores[tid + 256 * t];
    __syncthreads();
    int k = tid >> 3;          // box slot 0..31
    int s = tid & 7;           // segment 0..7
    int i = blockIdx.x * 32 + k;
    float si = sc[i];
    int cnt = 0;
    const float4* sc4 = (const float4*)sc;
    int q0 = s * (N_BOXES / 32);
    #pragma unroll 4
    for (int q = q0; q < q0 + N_BOXES / 32; ++q) {
        float4 v = sc4[q];
        int j = 4 * q;
        cnt += (int)((v.x > si) || (v.x == si && j     > i));
        cnt += (int)((v.y > si) || (v.y == si && j + 1 > i));
        cnt += (int)((v.z > si) || (v.z == si && j + 2 > i));
        cnt += (int)((v.w > si) || (v.w == si && j + 3 > i));
    }
    cnt += __shfl_down(cnt, 4, 8);
    cnt += __shfl_down(cnt, 2, 8);
    cnt += __shfl_down(cnt, 1, 8);
    if (s == 0) {
        int r = cnt;
        float x = bboxes[4 * i + 0], y = bboxes[4 * i + 1];
        float w = bboxes[4 * i + 2], h = bboxes[4 * i + 3];
        float x2 = x + w, y2 = y + h;           // exact ref op order
        x1s[r] = x; y1s[r] = y; x2s[r] = x2; y2s[r] = y2;
        rank_of[i] = (u32)r;
    }
}

// ---------------- Phase B: suppression bitmask matrix ----------------
// Row-major: RM[i*NW + cj] = word over j in chunk cj of sup(i->j) (j>i).
// TRb[d*N + j] (d=0..5) = word over i in chunk (chunk(j)-d) of sup(i->j).
__global__ void __launch_bounds__(256) mask_kernel(
        const float* __restrict__ x1s, const float* __restrict__ y1s,
        const float* __restrict__ x2s, const float* __restrict__ y2s,
        u64* __restrict__ RM, u64* __restrict__ TRb) {
    int wv = threadIdx.x >> 6, lane = threadIdx.x & 63;
    int ci = blockIdx.x;
    int cj = blockIdx.y * 4 + wv;
    if (cj < ci) return;
    __shared__ float S[4][4][64];
    int d = cj - ci;
    int ig0 = ci * 64, jg0 = cj * 64;
    if (d <= 5) {
        // ballot path: lanes = columns j; i-chunk staged in LDS
        S[wv][0][lane] = x1s[ig0 + lane];
        S[wv][1][lane] = y1s[ig0 + lane];
        S[wv][2][lane] = x2s[ig0 + lane];
        S[wv][3][lane] = y2s[ig0 + lane];
        int jg = jg0 + lane;
        float jx1 = x1s[jg], jy1 = y1s[jg], jx2 = x2s[jg], jy2 = y2s[jg];
        float jar = (jx2 - jx1) * (jy2 - jy1);   // bit-identical to ref area
        u64 my = 0, cw = 0;
        for (int ip = 0; ip < 64; ++ip) {
            float ax1 = S[wv][0][ip], ay1 = S[wv][1][ip];
            float ax2 = S[wv][2][ip], ay2 = S[wv][3][ip];
            float aar = (ax2 - ax1) * (ay2 - ay1);
            float xx1 = fmaxf(ax1, jx1);
            float yy1 = fmaxf(ay1, jy1);
            float xx2 = fminf(ax2, jx2);
            float yy2 = fminf(ay2, jy2);
            float iw = fmaxf(xx2 - xx1, 0.0f);
            float ih = fmaxf(yy2 - yy1, 0.0f);
            float inter = iw * ih;
            float uni = aar + jar - inter;
            float iou = __fdiv_rn(inter, uni);   // IEEE-exact like numpy
            bool sup = (iou > 0.5f) && (jg > ig0 + ip);
            u64 w = __ballot(sup);
            if (lane == ip) my = w;
            cw |= sup ? (1ull << ip) : 0ull;
        }
        RM[(size_t)(ig0 + lane) * NW + cj] = my;
        TRb[(size_t)d * N_BOXES + jg] = cw;
    } else {
        // direct path: lanes = rows i; j-chunk staged in LDS
        S[wv][0][lane] = x1s[jg0 + lane];
        S[wv][1][lane] = y1s[jg0 + lane];
        S[wv][2][lane] = x2s[jg0 + lane];
        S[wv][3][lane] = y2s[jg0 + lane];
        int ig = ig0 + lane;
        float ix1 = x1s[ig], iy1 = y1s[ig], ix2 = x2s[ig], iy2 = y2s[ig];
        float iar = (ix2 - ix1) * (iy2 - iy1);
        u64 my = 0;
        for (int jp = 0; jp < 64; ++jp) {
            float jx1 = S[wv][0][jp], jy1 = S[wv][1][jp];
            float jx2 = S[wv][2][jp], jy2 = S[wv][3][jp];
            float jar = (jx2 - jx1) * (jy2 - jy1);
            float xx1 = fmaxf(ix1, jx1);
            float yy1 = fmaxf(iy1, jy1);
            float xx2 = fminf(ix2, jx2);
            float yy2 = fminf(iy2, jy2);
            float iw = fmaxf(xx2 - xx1, 0.0f);
            float ih = fmaxf(yy2 - yy1, 0.0f);
            float inter = iw * ih;
            float uni = iar + jar - inter;
            float iou = __fdiv_rn(inter, uni);
            bool sup = (iou > 0.5f);             // cj>ci+5 => j>i always
            my |= sup ? (1ull << jp) : 0ull;
        }
        RM[(size_t)ig * NW + cj] = my;
    }
}

// ---------------- Phase C: greedy reduce (1 block, 4 waves) ----------------
// R12 structure (FIXPOINT, chunk-pair regions) with one change: 256 threads
// = 4 waves, one per SIMD. Wave0 (serial resolve) runs SOLO on SIMD0 -- no
// issue-slot competition from workers. Workers: wv1 owns words 2q+3+lane,
// wv2 owns +64 (same coverage as R12's wd0/wd1, split across waves), each
// holding all rows in NSLOT=8 slots; overflow (kept>8, first chunks only)
// falls to immediate loads at commit. wv3 idles (barriers only). All
// fold/deadline/tearing invariants verbatim R12.
__global__ void __launch_bounds__(256) nms_reduce(
        const u64* __restrict__ RM, const u64* __restrict__ TRb,
        u64* __restrict__ keepw_g) {
    __shared__ __align__(8) u32 rem32[NW * 2];
    __shared__ u64 keptw[NW];
    __shared__ unsigned char klA[4][64], klB[4][64];

    const int tid = threadIdx.x;
    const int wv = tid >> 6, lane = tid & 63;

    rem32[tid] = 0;                               // 256 threads == NW*2 slots

    u64 TDe[2], T1e[2], T2e[2], T3e[2], T4e[2];
    u64 TDo[2], T1o[2], T2o[2], T3o[2], T4o[2], T5o[2];
    u64 kp1 = 0, kp2 = 0, kp3 = 0, kp4 = 0;
    if (wv == 0) {     // region 0 set (chunks 0,1); unwritten planes masked by kp=0
        TDe[0] = TRb[lane];
        T1e[0] = TRb[N_BOXES + lane];
        T2e[0] = TRb[2 * N_BOXES + lane];
        T3e[0] = TRb[3 * N_BOXES + lane];
        T4e[0] = TRb[4 * N_BOXES + lane];
        TDo[0] = TRb[64 + lane];
        T1o[0] = TRb[N_BOXES + 64 + lane];        // d1[chunk1]: valid (fresh fold)
        T2o[0] = TRb[2 * N_BOXES + 64 + lane];
        T3o[0] = TRb[3 * N_BOXES + 64 + lane];
        T4o[0] = TRb[4 * N_BOXES + 64 + lane];
        T5o[0] = TRb[5 * N_BOXES + 64 + lane];
    }
    u64 HA[NSLOT], HB[NSLOT];
    #pragma unroll
    for (int s = 0; s < NSLOT; ++s) { HA[s] = 0; HB[s] = 0; }
    u32 KnA = 0, KnB = 0;
    __syncthreads();

#define FIXPOINT(TD, RIN, KOUT)                                                 \
    {                                                                           \
      u64 K = 0, U = ~(RIN);                                                    \
      bool meU = (U >> lane) & 1;                                               \
      while (U) {                                                               \
        u64 UK = U | K;                                                         \
        u64 nK = __ballot(meU && (((TD) & UK) == 0ull));                        \
        K |= nK;                                                                \
        u64 nR = __ballot(meU && (((TD) & K) != 0ull));                         \
        U &= ~(K | nR);                                                         \
        meU = (U >> lane) & 1;                                                  \
      }                                                                         \
      (KOUT) = K;                                                               \
    }

#define REGION(Q, PAR)                                                          \
  do {                                                                          \
    const int q_ = (Q);                                                         \
    const int c0 = 2 * q_, c1 = 2 * q_ + 1;                                     \
    if (wv == 0) {                                                              \
      /* both base reads up front: base1 latency hides under fixpoint0 */       \
      u64 base0 = *(const u64*)&rem32[2 * c0];                                  \
      u64 base1 = *(const u64*)&rem32[2 * c1];                                  \
      if (q_ + 1 < NREG) {            /* prefetch next region's TR set */       \
        const int n0 = (c0 + 2) * 64 + lane, n1 = n0 + 64;                      \
        TDe[PAR ^ 1] = TRb[n0];                                                 \
        T1e[PAR ^ 1] = TRb[N_BOXES + n0];                                       \
        T2e[PAR ^ 1] = TRb[2 * N_BOXES + n0];                                   \
        T3e[PAR ^ 1] = TRb[3 * N_BOXES + n0];                                   \
        T4e[PAR ^ 1] = TRb[4 * N_BOXES + n0];                                   \
        TDo[PAR ^ 1] = TRb[n1];                                                 \
        T1o[PAR ^ 1] = TRb[N_BOXES + n1];                                       \
        T2o[PAR ^ 1] = TRb[2 * N_BOXES + n1];                                   \
        T3o[PAR ^ 1] = TRb[3 * N_BOXES + n1];                                   \
        T4o[PAR ^ 1] = TRb[4 * N_BOXES + n1];                                   \
        T5o[PAR ^ 1] = TRb[5 * N_BOXES + n1];                                   \
      }                                                                         \
      u64 K0, K1;                                                               \
      {                                                                         \
        u64 R0 = base0 | __ballot(((T1e[PAR] & kp1) | (T2e[PAR] & kp2) |        \
                                   (T3e[PAR] & kp3) | (T4e[PAR] & kp4)) != 0ull);\
        FIXPOINT(TDe[PAR], R0, K0);                                             \
        bool isk = (K0 >> lane) & 1;                                            \
        int rnk = __popcll(K0 & ((1ull << lane) - 1ull));                       \
        if (isk) klA[q_ & 3][rnk] = (unsigned char)lane;                        \
        if (lane == 0) keptw[c0] = K0;                                          \
      }                                                                         \
      {                                                                         \
        u64 R1 = base1 | __ballot(((T1o[PAR] & K0)  | (T2o[PAR] & kp1) |        \
                                   (T3o[PAR] & kp2) | (T4o[PAR] & kp3) |        \
                                   (T5o[PAR] & kp4)) != 0ull);                  \
        FIXPOINT(TDo[PAR], R1, K1);                                             \
        bool isk = (K1 >> lane) & 1;                                            \
        int rnk = __popcll(K1 & ((1ull << lane) - 1ull));                       \
        if (isk) klB[q_ & 3][rnk] = (unsigned char)lane;                        \
        if (lane == 0) keptw[c1] = K1;                                          \
      }                                                                         \
      kp4 = kp2; kp3 = kp1; kp2 = K0; kp1 = K1;                                 \
    } else if (wv <= 2) {                                                       \
      /* COMMIT pair q_-2 (issued last region); my word wd >= 2q+1 */           \
      if (q_ >= 2 && (KnA | KnB)) {                                             \
        const int wd = 2 * q_ + 1 + lane + (wv - 1) * 64;                       \
        u64 v = 0;                                                              \
        _Pragma("unroll")                                                       \
        for (int s = 0; s < NSLOT; ++s) v |= HA[s] | HB[s];                     \
        if (KnA > (u32)NSLOT && wd < NW) {         /* rare overflow */          \
          const u32 cpb = (u32)(2 * q_ - 4) * 64u;                              \
          const unsigned char* kl = klA[(q_ - 2) & 3];                          \
          for (u32 r = (u32)NSLOT; r < KnA; ++r)                                \
            v |= RM[(size_t)(cpb + kl[r]) * NW + wd];                           \
        }                                                                       \
        if (KnB > (u32)NSLOT && wd < NW) {                                      \
          const u32 cpb = (u32)(2 * q_ - 3) * 64u;                              \
          const unsigned char* kl = klB[(q_ - 2) & 3];                          \
          for (u32 r = (u32)NSLOT; r < KnB; ++r)                                \
            v |= RM[(size_t)(cpb + kl[r]) * NW + wd];                           \
        }                                                                       \
        if (wd < NW && v) atomicOr((u64*)&rem32[2 * wd], v);                    \
      }                                                                         \
      /* ISSUE pair q_-1 (committed next region); words >= 2q+3 */              \
      {                                                                         \
        const int ib = 2 * q_ + 3;                                              \
        if (q_ >= 1 && ib < NW) {                                               \
          const u32 cA = (u32)(2 * q_ - 2) * 64u, cB = cA + 64u;                \
          KnA = (u32)__popcll(keptw[2 * q_ - 2]);                               \
          KnB = (u32)__popcll(keptw[2 * q_ - 1]);                               \
          const int wi = ib + lane + (wv - 1) * 64;                             \
          const unsigned char* kla = klA[(q_ - 1) & 3];                         \
          const unsigned char* klb = klB[(q_ - 1) & 3];                         \
          _Pragma("unroll")                                                     \
          for (int s = 0; s < NSLOT; ++s) {                                     \
            HA[s] = 0; HB[s] = 0;                                               \
            if ((u32)s < KnA && wi < NW)                                        \
              HA[s] = RM[(size_t)(cA + kla[s]) * NW + wi];                      \
            if ((u32)s < KnB && wi < NW)                                        \
              HB[s] = RM[(size_t)(cB + klb[s]) * NW + wi];                      \
          }                                                                     \
        } else { KnA = 0; KnB = 0; }                                            \
      }                                                                         \
    }                                                                           \
    barrier_nodrain();                                                          \
  } while (0)

    for (int qq = 0; qq < NREG; qq += 2) {
        REGION(qq, 0);
        REGION(qq + 1, 1);
    }
#undef REGION
#undef FIXPOINT

    __syncthreads();
    if (tid < NW) keepw_g[tid] = keptw[tid];
}

// ---------------- Phase D: regression + masked output (full grid) ----------
__global__ void output_kernel(const float* __restrict__ bboxes,
                              const float* __restrict__ features,
                              const float* __restrict__ Wm, const float* __restrict__ bv,
                              const int* __restrict__ widthp, const int* __restrict__ heightp,
                              const u32* __restrict__ rank_of, const u64* __restrict__ keepw,
                              float* __restrict__ out) {
    int i = blockIdx.x * blockDim.x + threadIdx.x;
    if (i >= N_BOXES) return;
    u32 r = rank_of[i];
    float keep = (float)((keepw[r >> 6] >> (r & 63)) & 1ull);
    float z0 = bv[0], z1 = bv[1], z2 = bv[2], z3 = bv[3];
    #pragma unroll
    for (int m = 0; m < FEAT; ++m) {
        float f = features[i * FEAT + m];
        z0 += f * Wm[m * 4 + 0];
        z1 += f * Wm[m * 4 + 1];
        z2 += f * Wm[m * 4 + 2];
        z3 += f * Wm[m * 4 + 3];
    }
    float t0 = 1.0f / (1.0f + expf(-z0));
    float t1 = 1.0f / (1.0f + expf(-z1));
    float t2 = 1.0f / (1.0f + expf(-z2));
    float t3 = 1.0f / (1.0f + expf(-z3));
    float4 bx = ((const float4*)bboxes)[i];
    float ox = fmaxf(t0 * bx.z + bx.x, 0.0f);
    float oy = fmaxf(t1 * bx.w + bx.y, 0.0f);
    float ow = bx.z * expf(t2);
    float oh = bx.w * expf(t3);
    float sw = (float)(*widthp), sh = (float)(*heightp);
    float4 o;
    o.x = ox * sw * keep;
    o.y = oy * sh * keep;
    o.z = ow * sw * keep;
    o.w = oh * sh * keep;
    ((float4*)out)[i] = o;
}

extern "C" void kernel_launch(void* const* d_in, const int* in_sizes, int n_in,
                              void* d_out, int out_size, void* d_ws, size_t ws_size,
                              hipStream_t stream) {
    const float* bboxes   = (const float*)d_in[0];
    const float* scores   = (const float*)d_in[1];
    const float* features = (const float*)d_in[2];
    const float* Wm       = (const float*)d_in[3];
    const float* bv       = (const float*)d_in[4];
    const int*   widthp   = (const int*)d_in[5];
    const int*   heightp  = (const int*)d_in[6];
    float* out = (float*)d_out;

    char* ws = (char*)d_ws;
    u64* RM      = (u64*)ws;                                        // 8 MiB
    u64* TRb     = (u64*)(ws + (size_t)N_BOXES * NW * sizeof(u64)); // 384 KiB (6 planes)
    float* x1s   = (float*)((char*)TRb + (size_t)6 * N_BOXES * sizeof(u64));
    float* y1s   = x1s + N_BOXES;
    float* x2s   = y1s + N_BOXES;
    float* y2s   = x2s + N_BOXES;
    u32* rank_of = (u32*)(y2s + N_BOXES);
    u64* keepw   = (u64*)(rank_of + N_BOXES);

    rank_scatter_kernel<<<N_BOXES / 32, 256, 0, stream>>>(bboxes, scores,
                                                          x1s, y1s, x2s, y2s, rank_of);
    mask_kernel<<<dim3(NW, NW / 4), 256, 0, stream>>>(x1s, y1s, x2s, y2s, RM, TRb);
    nms_reduce<<<1, 256, 0, stream>>>(RM, TRb, keepw);
    output_kernel<<<N_BOXES / 256, 256, 0, stream>>>(bboxes, features, Wm, bv,
                                                     widthp, heightp, rank_of, keepw, out);
}

// Round 17
// 131.341 us; speedup vs baseline: 2.0310x; 2.0310x over previous
//
#include <hip/hip_runtime.h>
#include <hip/hip_bf16.h>

#define N_BOXES 8192
#define NW 128            // number of 64-box chunks / 64-bit words per row
#define NREG 64           // regions (one chunk PAIR per region)
#define FEAT 10
#define NSLOT 4           // row slots per lane per chunk; 7 waves * 4 = 28 rows

typedef unsigned long long u64;
typedef unsigned int u32;

__device__ __forceinline__ void barrier_nodrain() {
    asm volatile("s_waitcnt lgkmcnt(0)" ::: "memory");
    __builtin_amdgcn_sched_barrier(0);
    __builtin_amdgcn_s_barrier();
    __builtin_amdgcn_sched_barrier(0);
    asm volatile("" ::: "memory");
}

// ---------------- Phase A: rank + scatter sorted boxes ----------------
__global__ void rank_scatter_kernel(const float* __restrict__ bboxes,
                                    const float* __restrict__ scores,
                                    float* __restrict__ x1s, float* __restrict__ y1s,
                                    float* __restrict__ x2s, float* __restrict__ y2s,
                                    u32* __restrict__ rank_of) {
    __shared__ float sc[N_BOXES];
    int tid = threadIdx.x;
    for (int t = 0; t < N_BOXES / 256; ++t)
        sc[tid + 256 * t] = scores[tid + 256 * t];
    __syncthreads();
    int k = tid >> 3;          // box slot 0..31
    int s = tid & 7;           // segment 0..7
    int i = blockIdx.x * 32 + k;
    float si = sc[i];
    int cnt = 0;
    const float4* sc4 = (const float4*)sc;
    int q0 = s * (N_BOXES / 32);
    #pragma unroll 4
    for (int q = q0; q < q0 + N_BOXES / 32; ++q) {
        float4 v = sc4[q];
        int j = 4 * q;
        cnt += (int)((v.x > si) || (v.x == si && j     > i));
        cnt += (int)((v.y > si) || (v.y == si && j + 1 > i));
        cnt += (int)((v.z > si) || (v.z == si && j + 2 > i));
        cnt += (int)((v.w > si) || (v.w == si && j + 3 > i));
    }
    cnt += __shfl_down(cnt, 4, 8);
    cnt += __shfl_down(cnt, 2, 8);
    cnt += __shfl_down(cnt, 1, 8);
    if (s == 0) {
        int r = cnt;
        float x = bboxes[4 * i + 0], y = bboxes[4 * i + 1];
        float w = bboxes[4 * i + 2], h = bboxes[4 * i + 3];
        float x2 = x + w, y2 = y + h;           // exact ref op order
        x1s[r] = x; y1s[r] = y; x2s[r] = x2; y2s[r] = y2;
        rank_of[i] = (u32)r;
    }
}

// ---------------- Phase B: suppression bitmask matrix ----------------
// Row-major: RM[i*NW + cj] = word over j in chunk cj of sup(i->j) (j>i).
// TRb[d*N + j] (d=0..5) = word over i in chunk (chunk(j)-d) of sup(i->j).
__global__ void __launch_bounds__(256) mask_kernel(
        const float* __restrict__ x1s, const float* __restrict__ y1s,
        const float* __restrict__ x2s, const float* __restrict__ y2s,
        u64* __restrict__ RM, u64* __restrict__ TRb) {
    int wv = threadIdx.x >> 6, lane = threadIdx.x & 63;
    int ci = blockIdx.x;
    int cj = blockIdx.y * 4 + wv;
    if (cj < ci) return;
    __shared__ float S[4][4][64];
    int d = cj - ci;
    int ig0 = ci * 64, jg0 = cj * 64;
    if (d <= 5) {
        // ballot path: lanes = columns j; i-chunk staged in LDS
        S[wv][0][lane] = x1s[ig0 + lane];
        S[wv][1][lane] = y1s[ig0 + lane];
        S[wv][2][lane] = x2s[ig0 + lane];
        S[wv][3][lane] = y2s[ig0 + lane];
        int jg = jg0 + lane;
        float jx1 = x1s[jg], jy1 = y1s[jg], jx2 = x2s[jg], jy2 = y2s[jg];
        float jar = (jx2 - jx1) * (jy2 - jy1);   // bit-identical to ref area
        u64 my = 0, cw = 0;
        for (int ip = 0; ip < 64; ++ip) {
            float ax1 = S[wv][0][ip], ay1 = S[wv][1][ip];
            float ax2 = S[wv][2][ip], ay2 = S[wv][3][ip];
            float aar = (ax2 - ax1) * (ay2 - ay1);
            float xx1 = fmaxf(ax1, jx1);
            float yy1 = fmaxf(ay1, jy1);
            float xx2 = fminf(ax2, jx2);
            float yy2 = fminf(ay2, jy2);
            float iw = fmaxf(xx2 - xx1, 0.0f);
            float ih = fmaxf(yy2 - yy1, 0.0f);
            float inter = iw * ih;
            float uni = aar + jar - inter;
            float iou = __fdiv_rn(inter, uni);   // IEEE-exact like numpy
            bool sup = (iou > 0.5f) && (jg > ig0 + ip);
            u64 w = __ballot(sup);
            if (lane == ip) my = w;
            cw |= sup ? (1ull << ip) : 0ull;
        }
        RM[(size_t)(ig0 + lane) * NW + cj] = my;
        TRb[(size_t)d * N_BOXES + jg] = cw;
    } else {
        // direct path: lanes = rows i; j-chunk staged in LDS
        S[wv][0][lane] = x1s[jg0 + lane];
        S[wv][1][lane] = y1s[jg0 + lane];
        S[wv][2][lane] = x2s[jg0 + lane];
        S[wv][3][lane] = y2s[jg0 + lane];
        int ig = ig0 + lane;
        float ix1 = x1s[ig], iy1 = y1s[ig], ix2 = x2s[ig], iy2 = y2s[ig];
        float iar = (ix2 - ix1) * (iy2 - iy1);
        u64 my = 0;
        for (int jp = 0; jp < 64; ++jp) {
            float jx1 = S[wv][0][jp], jy1 = S[wv][1][jp];
            float jx2 = S[wv][2][jp], jy2 = S[wv][3][jp];
            float jar = (jx2 - jx1) * (jy2 - jy1);
            float xx1 = fmaxf(ix1, jx1);
            float yy1 = fmaxf(iy1, jy1);
            float xx2 = fminf(ix2, jx2);
            float yy2 = fminf(iy2, jy2);
            float iw = fmaxf(xx2 - xx1, 0.0f);
            float ih = fmaxf(yy2 - yy1, 0.0f);
            float inter = iw * ih;
            float uni = iar + jar - inter;
            float iou = __fdiv_rn(inter, uni);
            bool sup = (iou > 0.5f);             // cj>ci+5 => j>i always
            my |= sup ? (1ull << jp) : 0ull;
        }
        RM[(size_t)ig * NW + cj] = my;
    }
}

// ---------------- Phase C: greedy reduce (1 block), chunk-pair regions -----
// R12 structure verbatim (FIXPOINT resolve; pair regions; 7 worker waves)
// plus two additions informed by R14/R16: (1) wave0 runs at s_setprio(1) --
// its serial cross-lane chain is the critical path and it SHARES a SIMD with
// a worker wave (8 waves / 4 SIMDs), so priority cuts issue interference in
// its latency windows; (2) both base LDS reads hoisted above the TR-prefetch
// burst so their latency overlaps the load issue.
__global__ void __launch_bounds__(512) nms_reduce(
        const u64* __restrict__ RM, const u64* __restrict__ TRb,
        u64* __restrict__ keepw_g) {
    __shared__ __align__(8) u32 rem32[NW * 2];
    __shared__ u64 keptw[NW];
    __shared__ unsigned char klA[4][64], klB[4][64];

    const int tid = threadIdx.x;
    const int wv = tid >> 6, lane = tid & 63;
    const int grp = wv - 1;                       // 0..6 for workers

    if (tid < NW * 2) rem32[tid] = 0;

    u64 TDe[2], T1e[2], T2e[2], T3e[2], T4e[2];
    u64 TDo[2], T1o[2], T2o[2], T3o[2], T4o[2], T5o[2];
    u64 kp1 = 0, kp2 = 0, kp3 = 0, kp4 = 0;
    if (wv == 0) {     // region 0 set (chunks 0,1); unwritten planes masked by kp=0
        __builtin_amdgcn_s_setprio(1);            // wave0 = the critical path
        TDe[0] = TRb[lane];
        T1e[0] = TRb[N_BOXES + lane];
        T2e[0] = TRb[2 * N_BOXES + lane];
        T3e[0] = TRb[3 * N_BOXES + lane];
        T4e[0] = TRb[4 * N_BOXES + lane];
        TDo[0] = TRb[64 + lane];
        T1o[0] = TRb[N_BOXES + 64 + lane];        // d1[chunk1]: valid (fresh fold)
        T2o[0] = TRb[2 * N_BOXES + 64 + lane];
        T3o[0] = TRb[3 * N_BOXES + 64 + lane];
        T4o[0] = TRb[4 * N_BOXES + 64 + lane];
        T5o[0] = TRb[5 * N_BOXES + 64 + lane];
    }
    u64 HA0[NSLOT], HA1[NSLOT], HB0[NSLOT], HB1[NSLOT];
    u32 KnA = 0, KnB = 0;
    __syncthreads();

#define FIXPOINT(TD, RIN, KOUT)                                                 \
    {                                                                           \
      u64 K = 0, U = ~(RIN);                                                    \
      bool meU = (U >> lane) & 1;                                               \
      while (U) {                                                               \
        u64 UK = U | K;                                                         \
        u64 nK = __ballot(meU && (((TD) & UK) == 0ull));                        \
        K |= nK;                                                                \
        u64 nR = __ballot(meU && (((TD) & K) != 0ull));                         \
        U &= ~(K | nR);                                                         \
        meU = (U >> lane) & 1;                                                  \
      }                                                                         \
      (KOUT) = K;                                                               \
    }

#define REGION(Q, PAR)                                                          \
  do {                                                                          \
    const int q_ = (Q);                                                         \
    const int c0 = 2 * q_, c1 = 2 * q_ + 1;                                     \
    if (wv == 0) {                                                              \
      /* base reads first: LDS latency hides under the prefetch burst */        \
      u64 base0 = *(const u64*)&rem32[2 * c0];                                  \
      u64 base1 = *(const u64*)&rem32[2 * c1];                                  \
      if (q_ + 1 < NREG) {            /* prefetch next region's TR set */       \
        const int n0 = (c0 + 2) * 64 + lane, n1 = n0 + 64;                      \
        TDe[PAR ^ 1] = TRb[n0];                                                 \
        T1e[PAR ^ 1] = TRb[N_BOXES + n0];                                       \
        T2e[PAR ^ 1] = TRb[2 * N_BOXES + n0];                                   \
        T3e[PAR ^ 1] = TRb[3 * N_BOXES + n0];                                   \
        T4e[PAR ^ 1] = TRb[4 * N_BOXES + n0];                                   \
        TDo[PAR ^ 1] = TRb[n1];                                                 \
        T1o[PAR ^ 1] = TRb[N_BOXES + n1];                                       \
        T2o[PAR ^ 1] = TRb[2 * N_BOXES + n1];                                   \
        T3o[PAR ^ 1] = TRb[3 * N_BOXES + n1];                                   \
        T4o[PAR ^ 1] = TRb[4 * N_BOXES + n1];                                   \
        T5o[PAR ^ 1] = TRb[5 * N_BOXES + n1];                                   \
      }                                                                         \
      u64 K0, K1;                                                               \
      {                                                                         \
        u64 R0 = base0 | __ballot(((T1e[PAR] & kp1) | (T2e[PAR] & kp2) |        \
                                   (T3e[PAR] & kp3) | (T4e[PAR] & kp4)) != 0ull);\
        FIXPOINT(TDe[PAR], R0, K0);                                             \
        bool isk = (K0 >> lane) & 1;                                            \
        int rnk = __popcll(K0 & ((1ull << lane) - 1ull));                       \
        if (isk) klA[q_ & 3][rnk] = (unsigned char)lane;                        \
        if (lane == 0) keptw[c0] = K0;                                          \
      }                                                                         \
      {                                                                         \
        u64 R1 = base1 | __ballot(((T1o[PAR] & K0)  | (T2o[PAR] & kp1) |        \
                                   (T3o[PAR] & kp2) | (T4o[PAR] & kp3) |        \
                                   (T5o[PAR] & kp4)) != 0ull);                  \
        FIXPOINT(TDo[PAR], R1, K1);                                             \
        bool isk = (K1 >> lane) & 1;                                            \
        int rnk = __popcll(K1 & ((1ull << lane) - 1ull));                       \
        if (isk) klB[q_ & 3][rnk] = (unsigned char)lane;                        \
        if (lane == 0) keptw[c1] = K1;                                          \
      }                                                                         \
      kp4 = kp2; kp3 = kp1; kp2 = K0; kp1 = K1;                                 \
    } else {                                                                    \
      /* COMMIT pair q_-2 (issued last region); words >= 2q+1 */                \
      if (q_ >= 2 && (KnA | KnB)) {                                             \
        const int wd0 = 2 * q_ + 1 + lane;                                      \
        const int wd1 = wd0 + 64;                                               \
        u64 v0 = 0, v1 = 0;                                                     \
        _Pragma("unroll")                                                       \
        for (int s = 0; s < NSLOT; ++s) {                                       \
          v0 |= HA0[s] | HB0[s];                                                \
          v1 |= HA1[s] | HB1[s];                                                \
        }                                                                       \
        if (KnA > 7u * NSLOT) {                    /* rare overflow */          \
          const u32 cpb = (u32)(2 * q_ - 4) * 64u;                              \
          const unsigned char* kl = klA[(q_ - 2) & 3];                          \
          for (u32 r = 7u * NSLOT + (u32)grp; r < KnA; r += 7u) {               \
            const u64* rp = RM + (size_t)(cpb + kl[r]) * NW;                    \
            if (wd0 < NW) v0 |= rp[wd0];                                        \
            if (wd1 < NW) v1 |= rp[wd1];                                        \
          }                                                                     \
        }                                                                       \
        if (KnB > 7u * NSLOT) {                                                 \
          const u32 cpb = (u32)(2 * q_ - 3) * 64u;                              \
          const unsigned char* kl = klB[(q_ - 2) & 3];                          \
          for (u32 r = 7u * NSLOT + (u32)grp; r < KnB; r += 7u) {               \
            const u64* rp = RM + (size_t)(cpb + kl[r]) * NW;                    \
            if (wd0 < NW) v0 |= rp[wd0];                                        \
            if (wd1 < NW) v1 |= rp[wd1];                                        \
          }                                                                     \
        }                                                                       \
        if (wd0 < NW && v0) atomicOr((u64*)&rem32[2 * wd0], v0);                \
        if (wd1 < NW && v1) atomicOr((u64*)&rem32[2 * wd1], v1);                \
      }                                                                         \
      /* ISSUE pair q_-1 (committed next region); words >= 2q+3 */              \
      {                                                                         \
        const int ib = 2 * q_ + 3;                                              \
        if (q_ >= 1 && ib < NW) {                                               \
          const u32 cA = (u32)(2 * q_ - 2) * 64u, cB = cA + 64u;                \
          KnA = (u32)__popcll(keptw[2 * q_ - 2]);                               \
          KnB = (u32)__popcll(keptw[2 * q_ - 1]);                               \
          const int wi0 = ib + lane;                                            \
          const int wi1 = wi0 + 64;                                             \
          const unsigned char* kla = klA[(q_ - 1) & 3];                         \
          const unsigned char* klb = klB[(q_ - 1) & 3];                         \
          _Pragma("unroll")                                                     \
          for (int s = 0; s < NSLOT; ++s) {                                     \
            HA0[s] = 0; HA1[s] = 0; HB0[s] = 0; HB1[s] = 0;                     \
            u32 r = (u32)(s * 7 + grp);            /* wave-uniform */           \
            if (r < KnA) {                                                      \
              const u64* rp = RM + (size_t)(cA + kla[r]) * NW;                  \
              if (wi0 < NW) HA0[s] = rp[wi0];                                   \
              if (wi1 < NW) HA1[s] = rp[wi1];                                   \
            }                                                                   \
            if (r < KnB) {                                                      \
              const u64* rp = RM + (size_t)(cB + klb[r]) * NW;                  \
              if (wi0 < NW) HB0[s] = rp[wi0];                                   \
              if (wi1 < NW) HB1[s] = rp[wi1];                                   \
            }                                                                   \
          }                                                                     \
        } else { KnA = 0; KnB = 0; }                                            \
      }                                                                         \
    }                                                                           \
    barrier_nodrain();                                                          \
  } while (0)

    for (int qq = 0; qq < NREG; qq += 2) {
        REGION(qq, 0);
        REGION(qq + 1, 1);
    }
#undef REGION
#undef FIXPOINT

    if (wv == 0) __builtin_amdgcn_s_setprio(0);
    __syncthreads();
    if (tid < NW) keepw_g[tid] = keptw[tid];
}

// ---------------- Phase D: regression + masked output (full grid) ----------
__global__ void output_kernel(const float* __restrict__ bboxes,
                              const float* __restrict__ features,
                              const float* __restrict__ Wm, const float* __restrict__ bv,
                              const int* __restrict__ widthp, const int* __restrict__ heightp,
                              const u32* __restrict__ rank_of, const u64* __restrict__ keepw,
                              float* __restrict__ out) {
    int i = blockIdx.x * blockDim.x + threadIdx.x;
    if (i >= N_BOXES) return;
    u32 r = rank_of[i];
    float keep = (float)((keepw[r >> 6] >> (r & 63)) & 1ull);
    float z0 = bv[0], z1 = bv[1], z2 = bv[2], z3 = bv[3];
    #pragma unroll
    for (int m = 0; m < FEAT; ++m) {
        float f = features[i * FEAT + m];
        z0 += f * Wm[m * 4 + 0];
        z1 += f * Wm[m * 4 + 1];
        z2 += f * Wm[m * 4 + 2];
        z3 += f * Wm[m * 4 + 3];
    }
    float t0 = 1.0f / (1.0f + expf(-z0));
    float t1 = 1.0f / (1.0f + expf(-z1));
    float t2 = 1.0f / (1.0f + expf(-z2));
    float t3 = 1.0f / (1.0f + expf(-z3));
    float4 bx = ((const float4*)bboxes)[i];
    float ox = fmaxf(t0 * bx.z + bx.x, 0.0f);
    float oy = fmaxf(t1 * bx.w + bx.y, 0.0f);
    float ow = bx.z * expf(t2);
    float oh = bx.w * expf(t3);
    float sw = (float)(*widthp), sh = (float)(*heightp);
    float4 o;
    o.x = ox * sw * keep;
    o.y = oy * sh * keep;
    o.z = ow * sw * keep;
    o.w = oh * sh * keep;
    ((float4*)out)[i] = o;
}

extern "C" void kernel_launch(void* const* d_in, const int* in_sizes, int n_in,
                              void* d_out, int out_size, void* d_ws, size_t ws_size,
                              hipStream_t stream) {
    const float* bboxes   = (const float*)d_in[0];
    const float* scores   = (const float*)d_in[1];
    const float* features = (const float*)d_in[2];
    const float* Wm       = (const float*)d_in[3];
    const float* bv       = (const float*)d_in[4];
    const int*   widthp   = (const int*)d_in[5];
    const int*   heightp  = (const int*)d_in[6];
    float* out = (float*)d_out;

    char* ws = (char*)d_ws;
    u64* RM      = (u64*)ws;                                        // 8 MiB
    u64* TRb     = (u64*)(ws + (size_t)N_BOXES * NW * sizeof(u64)); // 384 KiB (6 planes)
    float* x1s   = (float*)((char*)TRb + (size_t)6 * N_BOXES * sizeof(u64));
    float* y1s   = x1s + N_BOXES;
    float* x2s   = y1s + N_BOXES;
    float* y2s   = x2s + N_BOXES;
    u32* rank_of = (u32*)(y2s + N_BOXES);
    u64* keepw   = (u64*)(rank_of + N_BOXES);

    rank_scatter_kernel<<<N_BOXES / 32, 256, 0, stream>>>(bboxes, scores,
                                                          x1s, y1s, x2s, y2s, rank_of);
    mask_kernel<<<dim3(NW, NW / 4), 256, 0, stream>>>(x1s, y1s, x2s, y2s, RM, TRb);
    nms_reduce<<<1, 512, 0, stream>>>(RM, TRb, keepw);
    output_kernel<<<N_BOXES / 256, 256, 0, stream>>>(bboxes, features, Wm, bv,
                                                     widthp, heightp, rank_of, keepw, out);
}

// Round 18
// 124.629 us; speedup vs baseline: 2.1403x; 1.0539x over previous
//
#include <hip/hip_runtime.h>
#include <hip/hip_bf16.h>

#define N_BOXES 8192
#define NW 128            // number of 64-box chunks / 64-bit words per row
#define NREG 64           // regions (one chunk PAIR per region)
#define FEAT 10
#define NSLOT 4           // row slots per lane per chunk; 7 waves * 4 = 28 rows

typedef unsigned long long u64;
typedef unsigned int u32;

__device__ __forceinline__ void barrier_nodrain() {
    asm volatile("s_waitcnt lgkmcnt(0)" ::: "memory");
    __builtin_amdgcn_sched_barrier(0);
    __builtin_amdgcn_s_barrier();
    __builtin_amdgcn_sched_barrier(0);
    asm volatile("" ::: "memory");
}

// Exact-equivalent of (RN32(inter/uni) > 0.5f) for uni>=0, inter>=0, without
// the fp32 divide: RN(a/b) > 0.5 <=> a/b > 0.5*(1+2^-24) (midpoint; the tie
// rounds to even = 0.5 -> False on both formulations) <=> 2a > b*(1+2^-24).
// Evaluated in f64: f32->f64 exact; b's 24-bit mantissa x 25-bit constant
// = 49 bits < 53 -> product exact; comparison exact. uni=0,inter=0 case:
// numpy 0/0=NaN > 0.5 = False; here 0 > 0 = False -- matches.
__device__ __forceinline__ bool iou_gt_half(float inter, float uni) {
    return 2.0 * (double)inter > (double)uni * (1.0 + 0x1p-24);
}

// ---------------- Phase A: rank + scatter sorted boxes ----------------
__global__ void rank_scatter_kernel(const float* __restrict__ bboxes,
                                    const float* __restrict__ scores,
                                    float* __restrict__ x1s, float* __restrict__ y1s,
                                    float* __restrict__ x2s, float* __restrict__ y2s,
                                    float* __restrict__ areas, u32* __restrict__ rank_of) {
    __shared__ float sc[N_BOXES];
    int tid = threadIdx.x;
    for (int t = 0; t < N_BOXES / 256; ++t)
        sc[tid + 256 * t] = scores[tid + 256 * t];
    __syncthreads();
    int k = tid >> 3;          // box slot 0..31
    int s = tid & 7;           // segment 0..7
    int i = blockIdx.x * 32 + k;
    float si = sc[i];
    int cnt = 0;
    const float4* sc4 = (const float4*)sc;
    int q0 = s * (N_BOXES / 32);
    #pragma unroll 4
    for (int q = q0; q < q0 + N_BOXES / 32; ++q) {
        float4 v = sc4[q];
        int j = 4 * q;
        cnt += (int)((v.x > si) || (v.x == si && j     > i));
        cnt += (int)((v.y > si) || (v.y == si && j + 1 > i));
        cnt += (int)((v.z > si) || (v.z == si && j + 2 > i));
        cnt += (int)((v.w > si) || (v.w == si && j + 3 > i));
    }
    cnt += __shfl_down(cnt, 4, 8);
    cnt += __shfl_down(cnt, 2, 8);
    cnt += __shfl_down(cnt, 1, 8);
    if (s == 0) {
        int r = cnt;
        float x = bboxes[4 * i + 0], y = bboxes[4 * i + 1];
        float w = bboxes[4 * i + 2], h = bboxes[4 * i + 3];
        float x2 = x + w, y2 = y + h;           // exact ref op order
        x1s[r] = x; y1s[r] = y; x2s[r] = x2; y2s[r] = y2;
        areas[r] = (x2 - x) * (y2 - y);         // exact ref op order
        rank_of[i] = (u32)r;
    }
}

// ---------------- Phase B: suppression bitmask matrix ----------------
// Row-major: RM[i*NW + cj] = word over j in chunk cj of sup(i->j) (j>i).
// TRb[d*N + j] (d=0..5) = word over i in chunk (chunk(j)-d) of sup(i->j).
__global__ void __launch_bounds__(256) mask_kernel(
        const float* __restrict__ x1s, const float* __restrict__ y1s,
        const float* __restrict__ x2s, const float* __restrict__ y2s,
        const float* __restrict__ areas,
        u64* __restrict__ RM, u64* __restrict__ TRb) {
    int wv = threadIdx.x >> 6, lane = threadIdx.x & 63;
    int ci = blockIdx.x;
    int cj = blockIdx.y * 4 + wv;
    if (cj < ci) return;
    __shared__ float S[4][5][64];
    int d = cj - ci;
    int ig0 = ci * 64, jg0 = cj * 64;
    if (d <= 5) {
        // ballot path: lanes = columns j; i-chunk staged in LDS
        S[wv][0][lane] = x1s[ig0 + lane];
        S[wv][1][lane] = y1s[ig0 + lane];
        S[wv][2][lane] = x2s[ig0 + lane];
        S[wv][3][lane] = y2s[ig0 + lane];
        S[wv][4][lane] = areas[ig0 + lane];
        int jg = jg0 + lane;
        float jx1 = x1s[jg], jy1 = y1s[jg], jx2 = x2s[jg], jy2 = y2s[jg];
        float jar = areas[jg];
        u64 my = 0, cw = 0;
        for (int ip = 0; ip < 64; ++ip) {
            float xx1 = fmaxf(S[wv][0][ip], jx1);
            float yy1 = fmaxf(S[wv][1][ip], jy1);
            float xx2 = fminf(S[wv][2][ip], jx2);
            float yy2 = fminf(S[wv][3][ip], jy2);
            float iw = fmaxf(xx2 - xx1, 0.0f);
            float ih = fmaxf(yy2 - yy1, 0.0f);
            float inter = iw * ih;
            float uni = S[wv][4][ip] + jar - inter;   // exact ref op order
            bool sup = iou_gt_half(inter, uni) && (jg > ig0 + ip);
            u64 w = __ballot(sup);
            if (lane == ip) my = w;
            cw |= sup ? (1ull << ip) : 0ull;
        }
        RM[(size_t)(ig0 + lane) * NW + cj] = my;
        TRb[(size_t)d * N_BOXES + jg] = cw;
    } else {
        // direct path: lanes = rows i; j-chunk staged in LDS
        S[wv][0][lane] = x1s[jg0 + lane];
        S[wv][1][lane] = y1s[jg0 + lane];
        S[wv][2][lane] = x2s[jg0 + lane];
        S[wv][3][lane] = y2s[jg0 + lane];
        S[wv][4][lane] = areas[jg0 + lane];
        int ig = ig0 + lane;
        float ix1 = x1s[ig], iy1 = y1s[ig], ix2 = x2s[ig], iy2 = y2s[ig];
        float iar = areas[ig];
        u64 my = 0;
        for (int jp = 0; jp < 64; ++jp) {
            float xx1 = fmaxf(ix1, S[wv][0][jp]);
            float yy1 = fmaxf(iy1, S[wv][1][jp]);
            float xx2 = fminf(ix2, S[wv][2][jp]);
            float yy2 = fminf(iy2, S[wv][3][jp]);
            float iw = fmaxf(xx2 - xx1, 0.0f);
            float ih = fmaxf(yy2 - yy1, 0.0f);
            float inter = iw * ih;
            float uni = iar + S[wv][4][jp] - inter;   // exact ref op order
            bool sup = iou_gt_half(inter, uni);       // cj>ci+5 => j>i always
            my |= sup ? (1ull << jp) : 0ull;
        }
        RM[(size_t)ig * NW + cj] = my;
    }
}

// ---------------- Phase C: greedy reduce (1 block), chunk-pair regions -----
// R12/R17 structure verbatim (FIXPOINT resolve; pair regions; 7 worker
// waves; wave0 setprio + hoisted base reads). Proven at 65 us.
__global__ void __launch_bounds__(512) nms_reduce(
        const u64* __restrict__ RM, const u64* __restrict__ TRb,
        u64* __restrict__ keepw_g) {
    __shared__ __align__(8) u32 rem32[NW * 2];
    __shared__ u64 keptw[NW];
    __shared__ unsigned char klA[4][64], klB[4][64];

    const int tid = threadIdx.x;
    const int wv = tid >> 6, lane = tid & 63;
    const int grp = wv - 1;                       // 0..6 for workers

    if (tid < NW * 2) rem32[tid] = 0;

    u64 TDe[2], T1e[2], T2e[2], T3e[2], T4e[2];
    u64 TDo[2], T1o[2], T2o[2], T3o[2], T4o[2], T5o[2];
    u64 kp1 = 0, kp2 = 0, kp3 = 0, kp4 = 0;
    if (wv == 0) {     // region 0 set (chunks 0,1); unwritten planes masked by kp=0
        __builtin_amdgcn_s_setprio(1);            // wave0 = the critical path
        TDe[0] = TRb[lane];
        T1e[0] = TRb[N_BOXES + lane];
        T2e[0] = TRb[2 * N_BOXES + lane];
        T3e[0] = TRb[3 * N_BOXES + lane];
        T4e[0] = TRb[4 * N_BOXES + lane];
        TDo[0] = TRb[64 + lane];
        T1o[0] = TRb[N_BOXES + 64 + lane];        // d1[chunk1]: valid (fresh fold)
        T2o[0] = TRb[2 * N_BOXES + 64 + lane];
        T3o[0] = TRb[3 * N_BOXES + 64 + lane];
        T4o[0] = TRb[4 * N_BOXES + 64 + lane];
        T5o[0] = TRb[5 * N_BOXES + 64 + lane];
    }
    u64 HA0[NSLOT], HA1[NSLOT], HB0[NSLOT], HB1[NSLOT];
    u32 KnA = 0, KnB = 0;
    __syncthreads();

#define FIXPOINT(TD, RIN, KOUT)                                                 \
    {                                                                           \
      u64 K = 0, U = ~(RIN);                                                    \
      bool meU = (U >> lane) & 1;                                               \
      while (U) {                                                               \
        u64 UK = U | K;                                                         \
        u64 nK = __ballot(meU && (((TD) & UK) == 0ull));                        \
        K |= nK;                                                                \
        u64 nR = __ballot(meU && (((TD) & K) != 0ull));                         \
        U &= ~(K | nR);                                                         \
        meU = (U >> lane) & 1;                                                  \
      }                                                                         \
      (KOUT) = K;                                                               \
    }

#define REGION(Q, PAR)                                                          \
  do {                                                                          \
    const int q_ = (Q);                                                         \
    const int c0 = 2 * q_, c1 = 2 * q_ + 1;                                     \
    if (wv == 0) {                                                              \
      /* base reads first: LDS latency hides under the prefetch burst */        \
      u64 base0 = *(const u64*)&rem32[2 * c0];                                  \
      u64 base1 = *(const u64*)&rem32[2 * c1];                                  \
      if (q_ + 1 < NREG) {            /* prefetch next region's TR set */       \
        const int n0 = (c0 + 2) * 64 + lane, n1 = n0 + 64;                      \
        TDe[PAR ^ 1] = TRb[n0];                                                 \
        T1e[PAR ^ 1] = TRb[N_BOXES + n0];                                       \
        T2e[PAR ^ 1] = TRb[2 * N_BOXES + n0];                                   \
        T3e[PAR ^ 1] = TRb[3 * N_BOXES + n0];                                   \
        T4e[PAR ^ 1] = TRb[4 * N_BOXES + n0];                                   \
        TDo[PAR ^ 1] = TRb[n1];                                                 \
        T1o[PAR ^ 1] = TRb[N_BOXES + n1];                                       \
        T2o[PAR ^ 1] = TRb[2 * N_BOXES + n1];                                   \
        T3o[PAR ^ 1] = TRb[3 * N_BOXES + n1];                                   \
        T4o[PAR ^ 1] = TRb[4 * N_BOXES + n1];                                   \
        T5o[PAR ^ 1] = TRb[5 * N_BOXES + n1];                                   \
      }                                                                         \
      u64 K0, K1;                                                               \
      {                                                                         \
        u64 R0 = base0 | __ballot(((T1e[PAR] & kp1) | (T2e[PAR] & kp2) |        \
                                   (T3e[PAR] & kp3) | (T4e[PAR] & kp4)) != 0ull);\
        FIXPOINT(TDe[PAR], R0, K0);                                             \
        bool isk = (K0 >> lane) & 1;                                            \
        int rnk = __popcll(K0 & ((1ull << lane) - 1ull));                       \
        if (isk) klA[q_ & 3][rnk] = (unsigned char)lane;                        \
        if (lane == 0) keptw[c0] = K0;                                          \
      }                                                                         \
      {                                                                         \
        u64 R1 = base1 | __ballot(((T1o[PAR] & K0)  | (T2o[PAR] & kp1) |        \
                                   (T3o[PAR] & kp2) | (T4o[PAR] & kp3) |        \
                                   (T5o[PAR] & kp4)) != 0ull);                  \
        FIXPOINT(TDo[PAR], R1, K1);                                             \
        bool isk = (K1 >> lane) & 1;                                            \
        int rnk = __popcll(K1 & ((1ull << lane) - 1ull));                       \
        if (isk) klB[q_ & 3][rnk] = (unsigned char)lane;                        \
        if (lane == 0) keptw[c1] = K1;                                          \
      }                                                                         \
      kp4 = kp2; kp3 = kp1; kp2 = K0; kp1 = K1;                                 \
    } else {                                                                    \
      /* COMMIT pair q_-2 (issued last region); words >= 2q+1 */                \
      if (q_ >= 2 && (KnA | KnB)) {                                             \
        const int wd0 = 2 * q_ + 1 + lane;                                      \
        const int wd1 = wd0 + 64;                                               \
        u64 v0 = 0, v1 = 0;                                                     \
        _Pragma("unroll")                                                       \
        for (int s = 0; s < NSLOT; ++s) {                                       \
          v0 |= HA0[s] | HB0[s];                                                \
          v1 |= HA1[s] | HB1[s];                                                \
        }                                                                       \
        if (KnA > 7u * NSLOT) {                    /* rare overflow */          \
          const u32 cpb = (u32)(2 * q_ - 4) * 64u;                              \
          const unsigned char* kl = klA[(q_ - 2) & 3];                          \
          for (u32 r = 7u * NSLOT + (u32)grp; r < KnA; r += 7u) {               \
            const u64* rp = RM + (size_t)(cpb + kl[r]) * NW;                    \
            if (wd0 < NW) v0 |= rp[wd0];                                        \
            if (wd1 < NW) v1 |= rp[wd1];                                        \
          }                                                                     \
        }                                                                       \
        if (KnB > 7u * NSLOT) {                                                 \
          const u32 cpb = (u32)(2 * q_ - 3) * 64u;                              \
          const unsigned char* kl = klB[(q_ - 2) & 3];                          \
          for (u32 r = 7u * NSLOT + (u32)grp; r < KnB; r += 7u) {               \
            const u64* rp = RM + (size_t)(cpb + kl[r]) * NW;                    \
            if (wd0 < NW) v0 |= rp[wd0];                                        \
            if (wd1 < NW) v1 |= rp[wd1];                                        \
          }                                                                     \
        }                                                                       \
        if (wd0 < NW && v0) atomicOr((u64*)&rem32[2 * wd0], v0);                \
        if (wd1 < NW && v1) atomicOr((u64*)&rem32[2 * wd1], v1);                \
      }                                                                         \
      /* ISSUE pair q_-1 (committed next region); words >= 2q+3 */              \
      {                                                                         \
        const int ib = 2 * q_ + 3;                                              \
        if (q_ >= 1 && ib < NW) {                                               \
          const u32 cA = (u32)(2 * q_ - 2) * 64u, cB = cA + 64u;                \
          KnA = (u32)__popcll(keptw[2 * q_ - 2]);                               \
          KnB = (u32)__popcll(keptw[2 * q_ - 1]);                               \
          const int wi0 = ib + lane;                                            \
          const int wi1 = wi0 + 64;                                             \
          const unsigned char* kla = klA[(q_ - 1) & 3];                         \
          const unsigned char* klb = klB[(q_ - 1) & 3];                         \
          _Pragma("unroll")                                                     \
          for (int s = 0; s < NSLOT; ++s) {                                     \
            HA0[s] = 0; HA1[s] = 0; HB0[s] = 0; HB1[s] = 0;                     \
            u32 r = (u32)(s * 7 + grp);            /* wave-uniform */           \
            if (r < KnA) {                                                      \
              const u64* rp = RM + (size_t)(cA + kla[r]) * NW;                  \
              if (wi0 < NW) HA0[s] = rp[wi0];                                   \
              if (wi1 < NW) HA1[s] = rp[wi1];                                   \
            }                                                                   \
            if (r < KnB) {                                                      \
              const u64* rp = RM + (size_t)(cB + klb[r]) * NW;                  \
              if (wi0 < NW) HB0[s] = rp[wi0];                                   \
              if (wi1 < NW) HB1[s] = rp[wi1];                                   \
            }                                                                   \
          }                                                                     \
        } else { KnA = 0; KnB = 0; }                                            \
      }                                                                         \
    }                                                                           \
    barrier_nodrain();                                                          \
  } while (0)

    for (int qq = 0; qq < NREG; qq += 2) {
        REGION(qq, 0);
        REGION(qq + 1, 1);
    }
#undef REGION
#undef FIXPOINT

    if (wv == 0) __builtin_amdgcn_s_setprio(0);
    __syncthreads();
    if (tid < NW) keepw_g[tid] = keptw[tid];
}

// ---------------- Phase D: regression + masked output (full grid) ----------
__global__ void output_kernel(const float* __restrict__ bboxes,
                              const float* __restrict__ features,
                              const float* __restrict__ Wm, const float* __restrict__ bv,
                              const int* __restrict__ widthp, const int* __restrict__ heightp,
                              const u32* __restrict__ rank_of, const u64* __restrict__ keepw,
                              float* __restrict__ out) {
    int i = blockIdx.x * blockDim.x + threadIdx.x;
    if (i >= N_BOXES) return;
    u32 r = rank_of[i];
    float keep = (float)((keepw[r >> 6] >> (r & 63)) & 1ull);
    float z0 = bv[0], z1 = bv[1], z2 = bv[2], z3 = bv[3];
    #pragma unroll
    for (int m = 0; m < FEAT; ++m) {
        float f = features[i * FEAT + m];
        z0 += f * Wm[m * 4 + 0];
        z1 += f * Wm[m * 4 + 1];
        z2 += f * Wm[m * 4 + 2];
        z3 += f * Wm[m * 4 + 3];
    }
    float t0 = 1.0f / (1.0f + expf(-z0));
    float t1 = 1.0f / (1.0f + expf(-z1));
    float t2 = 1.0f / (1.0f + expf(-z2));
    float t3 = 1.0f / (1.0f + expf(-z3));
    float4 bx = ((const float4*)bboxes)[i];
    float ox = fmaxf(t0 * bx.z + bx.x, 0.0f);
    float oy = fmaxf(t1 * bx.w + bx.y, 0.0f);
    float ow = bx.z * expf(t2);
    float oh = bx.w * expf(t3);
    float sw = (float)(*widthp), sh = (float)(*heightp);
    float4 o;
    o.x = ox * sw * keep;
    o.y = oy * sh * keep;
    o.z = ow * sw * keep;
    o.w = oh * sh * keep;
    ((float4*)out)[i] = o;
}

extern "C" void kernel_launch(void* const* d_in, const int* in_sizes, int n_in,
                              void* d_out, int out_size, void* d_ws, size_t ws_size,
                              hipStream_t stream) {
    const float* bboxes   = (const float*)d_in[0];
    const float* scores   = (const float*)d_in[1];
    const float* features = (const float*)d_in[2];
    const float* Wm       = (const float*)d_in[3];
    const float* bv       = (const float*)d_in[4];
    const int*   widthp   = (const int*)d_in[5];
    const int*   heightp  = (const int*)d_in[6];
    float* out = (float*)d_out;

    char* ws = (char*)d_ws;
    u64* RM      = (u64*)ws;                                        // 8 MiB
    u64* TRb     = (u64*)(ws + (size_t)N_BOXES * NW * sizeof(u64)); // 384 KiB (6 planes)
    float* x1s   = (float*)((char*)TRb + (size_t)6 * N_BOXES * sizeof(u64));
    float* y1s   = x1s + N_BOXES;
    float* x2s   = y1s + N_BOXES;
    float* y2s   = x2s + N_BOXES;
    float* areas = y2s + N_BOXES;
    u32* rank_of = (u32*)(areas + N_BOXES);
    u64* keepw   = (u64*)(rank_of + N_BOXES);

    rank_scatter_kernel<<<N_BOXES / 32, 256, 0, stream>>>(bboxes, scores,
                                                          x1s, y1s, x2s, y2s, areas, rank_of);
    mask_kernel<<<dim3(NW, NW / 4), 256, 0, stream>>>(x1s, y1s, x2s, y2s, areas, RM, TRb);
    nms_reduce<<<1, 512, 0, stream>>>(RM, TRb, keepw);
    output_kernel<<<N_BOXES / 256, 256, 0, stream>>>(bboxes, features, Wm, bv,
                                                     widthp, heightp, rank_of, keepw, out);
}